// Round 1
// baseline (184.425 us; speedup 1.0000x reference)
//
#include <hip/hip_runtime.h>
#include <hip/hip_bf16.h>

#define NSEQ 4096
#define FT 256
#define BK 64

typedef __attribute__((ext_vector_type(8))) short bf16x8;
typedef __attribute__((ext_vector_type(4))) float f32x4;

__device__ __forceinline__ ushort f2bf(float f) {
  __hip_bfloat16 h = __float2bfloat16(f);
  return *reinterpret_cast<const ushort*>(&h);
}

// XOR swizzle within a 128B row: spreads the 16B granules so stride-128B
// column reads (ds_read_b128 fragments) hit all banks (2-way max = free).
__device__ __forceinline__ int swz(int row, int byteInRow) {
  return row * 128 + (byteInRow ^ ((row & 7) << 4));
}

// One BK=64 K-step: 12 ds_read_b128 + 16 MFMA per wave.
// A_lds: [64 rows(m)][64 k] bf16 swizzled; B_lds: [256 rows(n)][64 k] bf16 swizzled.
__device__ __forceinline__ void mma_step(const char* lAp, const char* lBp,
                                         int lane, int wm, int wn,
                                         f32x4 acc[2][4]) {
  const int r16 = lane & 15;
  const int g16 = (lane >> 4) * 16;
#pragma unroll
  for (int kk = 0; kk < 2; ++kk) {
    const int kb = kk * 64 + g16;
    bf16x8 a[2], b[4];
#pragma unroll
    for (int mi = 0; mi < 2; ++mi) {
      const int row = wm * 32 + mi * 16 + r16;
      a[mi] = *reinterpret_cast<const bf16x8*>(lAp + swz(row, kb));
    }
#pragma unroll
    for (int ni = 0; ni < 4; ++ni) {
      const int row = wn * 64 + ni * 16 + r16;
      b[ni] = *reinterpret_cast<const bf16x8*>(lBp + swz(row, kb));
    }
#pragma unroll
    for (int mi = 0; mi < 2; ++mi)
#pragma unroll
      for (int ni = 0; ni < 4; ++ni)
        acc[mi][ni] = __builtin_amdgcn_mfma_f32_16x16x32_bf16(a[mi], b[ni],
                                                             acc[mi][ni], 0, 0, 0);
  }
}

// ---------------- Kernel A: h = seq @ W^T + b, stored transposed bf16 ----------------
// Output: hT[batch][o][n]  (so kernel B can stage its B-operand contiguously)
// Grid: 256 blocks (64-row tiles of the flattened 16384 rows), 512 threads.
__global__ __launch_bounds__(512) void linear_kernel(
    const float* __restrict__ seq, const float* __restrict__ W,
    const float* __restrict__ bias, ushort* __restrict__ hT) {
  __shared__ __align__(16) ushort lA[2][64 * 64];
  __shared__ __align__(16) ushort lB[2][256 * 64];

  const int tid = threadIdx.x;
  const int lane = tid & 63;
  const int wid = tid >> 6;
  const int wm = wid >> 2, wn = wid & 3;
  const int m0 = blockIdx.x * 64;

  const int ar = tid >> 4, ac = tid & 15;

  float4 rA[2];
  float4 rB[8];

  auto gload = [&](int t) {
    const int k0 = t * BK;
#pragma unroll
    for (int p = 0; p < 2; ++p)
      rA[p] = *reinterpret_cast<const float4*>(
          seq + (size_t)(m0 + ar + p * 32) * FT + k0 + ac * 4);
#pragma unroll
    for (int p = 0; p < 8; ++p)
      rB[p] = *reinterpret_cast<const float4*>(
          W + (size_t)(ar + p * 32) * FT + k0 + ac * 4);
  };
  auto lwrite = [&](int buf) {
    char* lAp = (char*)lA[buf];
    char* lBp = (char*)lB[buf];
#pragma unroll
    for (int p = 0; p < 2; ++p) {
      ushort4 u = make_ushort4(f2bf(rA[p].x), f2bf(rA[p].y), f2bf(rA[p].z), f2bf(rA[p].w));
      *reinterpret_cast<ushort4*>(lAp + swz(ar + p * 32, ac * 8)) = u;
    }
#pragma unroll
    for (int p = 0; p < 8; ++p) {
      ushort4 u = make_ushort4(f2bf(rB[p].x), f2bf(rB[p].y), f2bf(rB[p].z), f2bf(rB[p].w));
      *reinterpret_cast<ushort4*>(lBp + swz(ar + p * 32, ac * 8)) = u;
    }
  };

  f32x4 acc[2][4];
  const f32x4 zero = {0.f, 0.f, 0.f, 0.f};
#pragma unroll
  for (int mi = 0; mi < 2; ++mi)
#pragma unroll
    for (int ni = 0; ni < 4; ++ni) acc[mi][ni] = zero;

  gload(0);
  lwrite(0);
  const int NT = FT / BK;  // 4
  for (int t = 0; t < NT; ++t) {
    const int cur = t & 1;
    __syncthreads();
    if (t + 1 < NT) gload(t + 1);
    mma_step((const char*)lA[cur], (const char*)lB[cur], lane, wm, wn, acc);
    if (t + 1 < NT) lwrite(cur ^ 1);
  }

  // Epilogue: +bias, cast bf16, store transposed. C/D layout: col=lane&15,
  // row=(lane>>4)*4+j -> 4 consecutive n per lane -> one 8B store per frag.
#pragma unroll
  for (int mi = 0; mi < 2; ++mi) {
    const int grow = m0 + wm * 32 + mi * 16 + ((lane >> 4) << 2);
    const int batch = grow >> 12;
    const int n = grow & (NSEQ - 1);
#pragma unroll
    for (int ni = 0; ni < 4; ++ni) {
      const int o = wn * 64 + ni * 16 + (lane & 15);
      const float bo = bias[o];
      ushort4 u;
      u.x = f2bf(acc[mi][ni][0] + bo);
      u.y = f2bf(acc[mi][ni][1] + bo);
      u.z = f2bf(acc[mi][ni][2] + bo);
      u.w = f2bf(acc[mi][ni][3] + bo);
      *reinterpret_cast<ushort4*>(hT + (size_t)(batch * FT + o) * NSEQ + n) = u;
    }
  }
}

// ---------------- Kernel B: out = PReLU(adj @ h) ----------------
// BM=64 (rows n), BN=256 (all features -> adj read exactly once), BK=64.
// Grid: 4 batches x 64 M-tiles = 256 blocks, 512 threads (8 waves as 2x4).
__global__ __launch_bounds__(512) void bmm_prelu_kernel(
    const float* __restrict__ adj, const ushort* __restrict__ hT,
    const float* __restrict__ alphaP, float* __restrict__ out) {
  __shared__ __align__(16) ushort lA[2][64 * 64];
  __shared__ __align__(16) ushort lB[2][256 * 64];

  const int tid = threadIdx.x;
  const int lane = tid & 63;
  const int wid = tid >> 6;
  const int wm = wid >> 2, wn = wid & 3;

  const int batch = blockIdx.x >> 6;
  const int mtile = blockIdx.x & 63;
  const int m0 = mtile * 64;

  const float* adjB = adj + (size_t)batch * NSEQ * NSEQ + (size_t)m0 * NSEQ;
  const ushort* hTB = hT + (size_t)batch * FT * NSEQ;

  const int ar = tid >> 4, ac = tid & 15;  // A staging: 32 rows per pass
  const int br = tid >> 3, bc = tid & 7;   // B staging: 64 rows per pass

  float4 rA[2];
  uint4 rB[4];

  auto gload = [&](int t) {
    const int k0 = t * BK;
#pragma unroll
    for (int p = 0; p < 2; ++p)
      rA[p] = *reinterpret_cast<const float4*>(
          adjB + (size_t)(ar + p * 32) * NSEQ + k0 + ac * 4);
#pragma unroll
    for (int p = 0; p < 4; ++p)
      rB[p] = *reinterpret_cast<const uint4*>(
          hTB + (size_t)(br + p * 64) * NSEQ + k0 + bc * 8);
  };
  auto lwrite = [&](int buf) {
    char* lAp = (char*)lA[buf];
    char* lBp = (char*)lB[buf];
#pragma unroll
    for (int p = 0; p < 2; ++p) {
      ushort4 u = make_ushort4(f2bf(rA[p].x), f2bf(rA[p].y), f2bf(rA[p].z), f2bf(rA[p].w));
      *reinterpret_cast<ushort4*>(lAp + swz(ar + p * 32, ac * 8)) = u;
    }
#pragma unroll
    for (int p = 0; p < 4; ++p)
      *reinterpret_cast<uint4*>(lBp + swz(br + p * 64, bc * 16)) = rB[p];
  };

  f32x4 acc[2][4];
  const f32x4 zero = {0.f, 0.f, 0.f, 0.f};
#pragma unroll
  for (int mi = 0; mi < 2; ++mi)
#pragma unroll
    for (int ni = 0; ni < 4; ++ni) acc[mi][ni] = zero;

  gload(0);
  lwrite(0);
  const int NT = NSEQ / BK;  // 64
  for (int t = 0; t < NT; ++t) {
    const int cur = t & 1;
    __syncthreads();
    if (t + 1 < NT) gload(t + 1);
    mma_step((const char*)lA[cur], (const char*)lB[cur], lane, wm, wn, acc);
    if (t + 1 < NT) lwrite(cur ^ 1);
  }

  const float alpha = *alphaP;
  float* outB = out + ((size_t)batch * NSEQ + m0) * FT;
#pragma unroll
  for (int mi = 0; mi < 2; ++mi) {
    const int rbase = wm * 32 + mi * 16 + ((lane >> 4) << 2);
#pragma unroll
    for (int ni = 0; ni < 4; ++ni) {
      const int o = wn * 64 + ni * 16 + (lane & 15);
#pragma unroll
      for (int j = 0; j < 4; ++j) {
        float v = acc[mi][ni][j];
        v = v > 0.f ? v : alpha * v;
        outB[(size_t)(rbase + j) * FT + o] = v;
      }
    }
  }
}

extern "C" void kernel_launch(void* const* d_in, const int* in_sizes, int n_in,
                              void* d_out, int out_size, void* d_ws, size_t ws_size,
                              hipStream_t stream) {
  const float* seq = (const float*)d_in[0];
  const float* adj = (const float*)d_in[1];
  const float* W = (const float*)d_in[2];
  const float* bias = (const float*)d_in[3];
  const float* alpha = (const float*)d_in[4];
  float* out = (float*)d_out;
  ushort* hT = (ushort*)d_ws;  // [4][256][4096] bf16 = 8 MB

  linear_kernel<<<256, 512, 0, stream>>>(seq, W, bias, hT);
  bmm_prelu_kernel<<<256, 512, 0, stream>>>(adj, hT, alpha, out);
}

// Round 2
// 114.449 us; speedup vs baseline: 1.6114x; 1.6114x over previous
//
#include <hip/hip_runtime.h>
#include <hip/hip_bf16.h>

#define NSEQ 4096
#define FT 256
#define BK 64
#define NT (NSEQ / BK)  // 64

typedef __attribute__((ext_vector_type(8))) short bf16x8;
typedef __attribute__((ext_vector_type(4))) float f32x4;

__device__ __forceinline__ ushort f2bf(float f) {
  __hip_bfloat16 h = __float2bfloat16(f);
  return *reinterpret_cast<const ushort*>(&h);
}

// XOR swizzle of 16B granules within a 128B row.
__device__ __forceinline__ int swz(int row, int byteInRow) {
  return row * 128 + (byteInRow ^ ((row & 7) << 4));
}

// One BK=64 K-step: 12 ds_read_b128 + 16 MFMA per wave.
__device__ __forceinline__ void mma_step(const char* lAp, const char* lBp,
                                         int lane, int wm, int wn,
                                         f32x4 acc[2][4]) {
  const int r16 = lane & 15;
  const int g16 = (lane >> 4) * 16;
#pragma unroll
  for (int kk = 0; kk < 2; ++kk) {
    const int kb = kk * 64 + g16;
    bf16x8 a[2], b[4];
#pragma unroll
    for (int mi = 0; mi < 2; ++mi) {
      const int row = wm * 32 + mi * 16 + r16;
      a[mi] = *reinterpret_cast<const bf16x8*>(lAp + swz(row, kb));
    }
#pragma unroll
    for (int ni = 0; ni < 4; ++ni) {
      const int row = wn * 64 + ni * 16 + r16;
      b[ni] = *reinterpret_cast<const bf16x8*>(lBp + swz(row, kb));
    }
#pragma unroll
    for (int mi = 0; mi < 2; ++mi)
#pragma unroll
      for (int ni = 0; ni < 4; ++ni)
        acc[mi][ni] = __builtin_amdgcn_mfma_f32_16x16x32_bf16(a[mi], b[ni],
                                                             acc[mi][ni], 0, 0, 0);
  }
}

// ---------------- Kernel A: hT[b][o][n] = (seq @ W^T + b) as bf16 ----------------
__global__ __launch_bounds__(512) void linear_kernel(
    const float* __restrict__ seq, const float* __restrict__ W,
    const float* __restrict__ bias, ushort* __restrict__ hT) {
  __shared__ __align__(16) ushort lA[2][64 * 64];
  __shared__ __align__(16) ushort lB[2][256 * 64];

  const int tid = threadIdx.x;
  const int lane = tid & 63;
  const int wid = tid >> 6;
  const int wm = wid >> 2, wn = wid & 3;
  const int m0 = blockIdx.x * 64;

  const int ar = tid >> 4, ac = tid & 15;

  float4 rA[2];
  float4 rB[8];

  auto gload = [&](int t) {
    const int k0 = t * BK;
#pragma unroll
    for (int p = 0; p < 2; ++p)
      rA[p] = *reinterpret_cast<const float4*>(
          seq + (size_t)(m0 + ar + p * 32) * FT + k0 + ac * 4);
#pragma unroll
    for (int p = 0; p < 8; ++p)
      rB[p] = *reinterpret_cast<const float4*>(
          W + (size_t)(ar + p * 32) * FT + k0 + ac * 4);
  };
  auto lwrite = [&](int buf) {
    char* lAp = (char*)lA[buf];
    char* lBp = (char*)lB[buf];
#pragma unroll
    for (int p = 0; p < 2; ++p) {
      ushort4 u = make_ushort4(f2bf(rA[p].x), f2bf(rA[p].y), f2bf(rA[p].z), f2bf(rA[p].w));
      *reinterpret_cast<ushort4*>(lAp + swz(ar + p * 32, ac * 8)) = u;
    }
#pragma unroll
    for (int p = 0; p < 8; ++p) {
      ushort4 u = make_ushort4(f2bf(rB[p].x), f2bf(rB[p].y), f2bf(rB[p].z), f2bf(rB[p].w));
      *reinterpret_cast<ushort4*>(lBp + swz(ar + p * 32, ac * 8)) = u;
    }
  };

  f32x4 acc[2][4];
  const f32x4 zero = {0.f, 0.f, 0.f, 0.f};
#pragma unroll
  for (int mi = 0; mi < 2; ++mi)
#pragma unroll
    for (int ni = 0; ni < 4; ++ni) acc[mi][ni] = zero;

  gload(0);
  lwrite(0);
  const int NTA = FT / BK;  // 4
  for (int t = 0; t < NTA; ++t) {
    const int cur = t & 1;
    __syncthreads();
    if (t + 1 < NTA) gload(t + 1);
    mma_step((const char*)lA[cur], (const char*)lB[cur], lane, wm, wn, acc);
    if (t + 1 < NTA) lwrite(cur ^ 1);
  }

#pragma unroll
  for (int mi = 0; mi < 2; ++mi) {
    const int grow = m0 + wm * 32 + mi * 16 + ((lane >> 4) << 2);
    const int batch = grow >> 12;
    const int n = grow & (NSEQ - 1);
#pragma unroll
    for (int ni = 0; ni < 4; ++ni) {
      const int o = wn * 64 + ni * 16 + (lane & 15);
      const float bo = bias[o];
      ushort4 u;
      u.x = f2bf(acc[mi][ni][0] + bo);
      u.y = f2bf(acc[mi][ni][1] + bo);
      u.z = f2bf(acc[mi][ni][2] + bo);
      u.w = f2bf(acc[mi][ni][3] + bo);
      *reinterpret_cast<ushort4*>(hT + (size_t)(batch * FT + o) * NSEQ + n) = u;
    }
  }
}

// ---------------- Kernel B: out = PReLU(adj @ h), pipelined ----------------
// BM=64, BN=256 (adj read once), BK=64. 512 thr (8 waves 2x4), grid 256.
// hT staged via global_load_lds (pre-swizzled source), 3 buffers, 2-deep.
// adj reg-staged 2-deep (fp32->bf16 cvt). Counted vmcnt: 10 / 6, never 0
// in steady state.
__global__ __launch_bounds__(512) void bmm_prelu_kernel(
    const float* __restrict__ adj, const ushort* __restrict__ hT,
    const float* __restrict__ alphaP, float* __restrict__ out) {
  __shared__ __align__(16) ushort lA[2][64 * 64];
  __shared__ __align__(16) ushort lB[3][256 * 64];

  const int tid = threadIdx.x;
  const int lane = tid & 63;
  const int wid = tid >> 6;
  const int wm = wid >> 2, wn = wid & 3;

  // XCD-contiguous remap: launch-id L -> XCD L%8 gets contiguous work chunk.
  const int bid = blockIdx.x;
  const int sbid = (bid & 7) * 32 + (bid >> 3);
  const int batch = sbid >> 6;
  const int m0 = (sbid & 63) * 64;

  const float* adjB = adj + (size_t)batch * NSEQ * NSEQ + (size_t)m0 * NSEQ;
  const ushort* hTB = hT + (size_t)batch * FT * NSEQ;

  const int ar = tid >> 4, ac = tid & 15;      // adj staging geometry
  const int brow = wid * 8 + (lane >> 3);      // hT row (+ p*64)
  const int bg = (lane & 7) ^ (lane >> 3);     // pre-swizzled source granule

  float4 rA0[2], rA1[2];

  f32x4 acc[2][4];
  const f32x4 zero = {0.f, 0.f, 0.f, 0.f};
#pragma unroll
  for (int mi = 0; mi < 2; ++mi)
#pragma unroll
    for (int ni = 0; ni < 4; ++ni) acc[mi][ni] = zero;

  auto issueA = [&](int t, float4* r) {
    const int k0 = t * BK;
#pragma unroll
    for (int p = 0; p < 2; ++p)
      r[p] = *reinterpret_cast<const float4*>(
          adjB + (size_t)(ar + p * 32) * NSEQ + k0 + ac * 4);
  };
  auto issueB = [&](int t, int ib) {
    const int k0 = t * BK;
#pragma unroll
    for (int p = 0; p < 4; ++p) {
      const ushort* gp = hTB + (size_t)(p * 64 + brow) * NSEQ + k0 + bg * 8;
      // wave-uniform LDS base; HW adds lane*16B -> linear fill equals
      // swizzled layout because the SOURCE granule is pre-swizzled.
      ushort* lp = &lB[ib][p * 4096 + wid * 512];
      __builtin_amdgcn_global_load_lds(
          (const __attribute__((address_space(1))) void*)gp,
          (__attribute__((address_space(3))) void*)lp, 16, 0, 0);
    }
  };
  auto writeA = [&](const float4* r, int ia) {
    char* lAp = (char*)lA[ia];
#pragma unroll
    for (int p = 0; p < 2; ++p) {
      ushort4 u = make_ushort4(f2bf(r[p].x), f2bf(r[p].y), f2bf(r[p].z), f2bf(r[p].w));
      *reinterpret_cast<ushort4*>(lAp + swz(ar + p * 32, ac * 8)) = u;
    }
  };

  // Prologue: stage tiles 0 and 1. Queue: A0(2) B0(4) A1(2) B1(4).
  issueA(0, rA0);
  issueB(0, 0);
  issueA(1, rA1);
  issueB(1, 1);
  asm volatile("s_waitcnt vmcnt(10)" ::: "memory");  // A0 done
  writeA(rA0, 0);
  asm volatile("s_waitcnt vmcnt(6) lgkmcnt(0)" ::: "memory");  // B0 done
  __builtin_amdgcn_s_barrier();
  __builtin_amdgcn_sched_barrier(0);

  auto body = [&](int t, float4* rIssue, float4* rWrite) {
    const int ibR = t % 3;
    const int ibW = (t + 2) % 3;
    issueA(t + 2, rIssue);  // +2 vm (issued before B so counted waits work)
    issueB(t + 2, ibW);     // +4 vm
    mma_step((const char*)lA[t & 1], (const char*)lB[ibR], lane, wm, wn, acc);
    asm volatile("s_waitcnt vmcnt(10)" ::: "memory");  // A(t+1) regs ready
    writeA(rWrite, (t + 1) & 1);
    asm volatile("s_waitcnt vmcnt(6) lgkmcnt(0)" ::: "memory");  // B(t+1) done
    __builtin_amdgcn_s_barrier();
    __builtin_amdgcn_sched_barrier(0);
  };

  // 2x unrolled so register-set parity is static (no scratch spill).
  for (int t = 0; t < NT - 2; t += 2) {
    body(t, rA0, rA1);
    body(t + 1, rA1, rA0);
  }
  {  // t = NT-2: in flight A(NT-1)=2, B(NT-1)=4
    const int t = NT - 2;
    mma_step((const char*)lA[t & 1], (const char*)lB[t % 3], lane, wm, wn, acc);
    asm volatile("s_waitcnt vmcnt(4)" ::: "memory");
    writeA(rA1, (t + 1) & 1);
    asm volatile("s_waitcnt vmcnt(0) lgkmcnt(0)" ::: "memory");
    __builtin_amdgcn_s_barrier();
    __builtin_amdgcn_sched_barrier(0);
  }
  {
    const int t = NT - 1;
    mma_step((const char*)lA[t & 1], (const char*)lB[t % 3], lane, wm, wn, acc);
  }

  // Epilogue: PReLU -> LDS (reuse lB, padded pitch) -> coalesced float4 rows.
  const float alpha = *alphaP;
  __syncthreads();
  float* lo = (float*)&lB[0][0];  // 64 x 264 f32 = 66 KB <= 96 KB
  const int PITCH = 264;
#pragma unroll
  for (int mi = 0; mi < 2; ++mi) {
    const int rbase = wm * 32 + mi * 16 + ((lane >> 4) << 2);
#pragma unroll
    for (int ni = 0; ni < 4; ++ni) {
      const int o = wn * 64 + ni * 16 + (lane & 15);
#pragma unroll
      for (int j = 0; j < 4; ++j) {
        float v = acc[mi][ni][j];
        v = v > 0.f ? v : alpha * v;
        lo[(rbase + j) * PITCH + o] = v;
      }
    }
  }
  __syncthreads();
  float* outB = out + ((size_t)batch * NSEQ + m0) * FT;
  const int r = tid >> 3, c8 = tid & 7;
#pragma unroll
  for (int k = 0; k < 8; ++k) {
    const int g = c8 + k * 8;
    float4 v = *reinterpret_cast<const float4*>(lo + r * PITCH + g * 4);
    *reinterpret_cast<float4*>(outB + (size_t)r * FT + g * 4) = v;
  }
}

extern "C" void kernel_launch(void* const* d_in, const int* in_sizes, int n_in,
                              void* d_out, int out_size, void* d_ws, size_t ws_size,
                              hipStream_t stream) {
  const float* seq = (const float*)d_in[0];
  const float* adj = (const float*)d_in[1];
  const float* W = (const float*)d_in[2];
  const float* bias = (const float*)d_in[3];
  const float* alpha = (const float*)d_in[4];
  float* out = (float*)d_out;
  ushort* hT = (ushort*)d_ws;  // [4][256][4096] bf16 = 8 MB

  linear_kernel<<<256, 512, 0, stream>>>(seq, W, bias, hT);
  bmm_prelu_kernel<<<256, 512, 0, stream>>>(adj, hT, alpha, out);
}

// Round 4
// 93.594 us; speedup vs baseline: 1.9705x; 1.2228x over previous
//
#include <hip/hip_runtime.h>
#include <hip/hip_bf16.h>

#define NSEQ 4096
#define FT 256
#define BK 64
#define NT (NSEQ / BK)  // 64

typedef __attribute__((ext_vector_type(8))) short bf16x8;
typedef __attribute__((ext_vector_type(4))) float f32x4;

__device__ __forceinline__ ushort f2bf(float f) {
  __hip_bfloat16 h = __float2bfloat16(f);
  return *reinterpret_cast<const ushort*>(&h);
}

// XOR swizzle of 16B granules within a 128B row.
__device__ __forceinline__ int swz(int row, int byteInRow) {
  return row * 128 + (byteInRow ^ ((row & 7) << 4));
}

// One BK=64 K-step: 12 ds_read_b128 + 16 MFMA per wave.
__device__ __forceinline__ void mma_step(const char* lAp, const char* lBp,
                                         int lane, int wm, int wn,
                                         f32x4 acc[2][4]) {
  const int r16 = lane & 15;
  const int g16 = (lane >> 4) * 16;
#pragma unroll
  for (int kk = 0; kk < 2; ++kk) {
    const int kb = kk * 64 + g16;
    bf16x8 a[2], b[4];
#pragma unroll
    for (int mi = 0; mi < 2; ++mi) {
      const int row = wm * 32 + mi * 16 + r16;
      a[mi] = *reinterpret_cast<const bf16x8*>(lAp + swz(row, kb));
    }
#pragma unroll
    for (int ni = 0; ni < 4; ++ni) {
      const int row = wn * 64 + ni * 16 + r16;
      b[ni] = *reinterpret_cast<const bf16x8*>(lBp + swz(row, kb));
    }
#pragma unroll
    for (int mi = 0; mi < 2; ++mi)
#pragma unroll
      for (int ni = 0; ni < 4; ++ni)
        acc[mi][ni] = __builtin_amdgcn_mfma_f32_16x16x32_bf16(a[mi], b[ni],
                                                             acc[mi][ni], 0, 0, 0);
  }
}

// ---------------- Kernel A: hT[b][o][n] = (seq @ W^T + b) as bf16 ----------------
__global__ __launch_bounds__(512) void linear_kernel(
    const float* __restrict__ seq, const float* __restrict__ W,
    const float* __restrict__ bias, ushort* __restrict__ hT) {
  __shared__ __align__(16) ushort lA[2][64 * 64];
  __shared__ __align__(16) ushort lB[2][256 * 64];

  const int tid = threadIdx.x;
  const int lane = tid & 63;
  const int wid = tid >> 6;
  const int wm = wid >> 2, wn = wid & 3;
  const int m0 = blockIdx.x * 64;

  const int ar = tid >> 4, ac = tid & 15;

  f32x4 rA[2];
  f32x4 rB[8];

  auto gload = [&](int t) {
    const int k0 = t * BK;
#pragma unroll
    for (int p = 0; p < 2; ++p)
      rA[p] = *reinterpret_cast<const f32x4*>(
          seq + (size_t)(m0 + ar + p * 32) * FT + k0 + ac * 4);
#pragma unroll
    for (int p = 0; p < 8; ++p)
      rB[p] = *reinterpret_cast<const f32x4*>(
          W + (size_t)(ar + p * 32) * FT + k0 + ac * 4);
  };
  auto lwrite = [&](int buf) {
    char* lAp = (char*)lA[buf];
    char* lBp = (char*)lB[buf];
#pragma unroll
    for (int p = 0; p < 2; ++p) {
      ushort4 u = make_ushort4(f2bf(rA[p][0]), f2bf(rA[p][1]), f2bf(rA[p][2]), f2bf(rA[p][3]));
      *reinterpret_cast<ushort4*>(lAp + swz(ar + p * 32, ac * 8)) = u;
    }
#pragma unroll
    for (int p = 0; p < 8; ++p) {
      ushort4 u = make_ushort4(f2bf(rB[p][0]), f2bf(rB[p][1]), f2bf(rB[p][2]), f2bf(rB[p][3]));
      *reinterpret_cast<ushort4*>(lBp + swz(ar + p * 32, ac * 8)) = u;
    }
  };

  f32x4 acc[2][4];
  const f32x4 zero = {0.f, 0.f, 0.f, 0.f};
#pragma unroll
  for (int mi = 0; mi < 2; ++mi)
#pragma unroll
    for (int ni = 0; ni < 4; ++ni) acc[mi][ni] = zero;

  gload(0);
  lwrite(0);
  const int NTA = FT / BK;  // 4
  for (int t = 0; t < NTA; ++t) {
    const int cur = t & 1;
    __syncthreads();
    if (t + 1 < NTA) gload(t + 1);
    mma_step((const char*)lA[cur], (const char*)lB[cur], lane, wm, wn, acc);
    if (t + 1 < NTA) lwrite(cur ^ 1);
  }

#pragma unroll
  for (int mi = 0; mi < 2; ++mi) {
    const int grow = m0 + wm * 32 + mi * 16 + ((lane >> 4) << 2);
    const int batch = grow >> 12;
    const int n = grow & (NSEQ - 1);
#pragma unroll
    for (int ni = 0; ni < 4; ++ni) {
      const int o = wn * 64 + ni * 16 + (lane & 15);
      const float bo = bias[o];
      ushort4 u;
      u.x = f2bf(acc[mi][ni][0] + bo);
      u.y = f2bf(acc[mi][ni][1] + bo);
      u.z = f2bf(acc[mi][ni][2] + bo);
      u.w = f2bf(acc[mi][ni][3] + bo);
      *reinterpret_cast<ushort4*>(hT + (size_t)(batch * FT + o) * NSEQ + n) = u;
    }
  }
}

// ---------------- Kernel B: out = PReLU(adj @ h), deep-pipelined ----------------
// BM=64, BN=256 (adj read once), BK=64. 512 thr (8 waves 2x4), grid 256.
// hT: global_load_lds, 4 LDS buffers, 3-deep prefetch. adj: nontemporal
// reg-staged, 2-deep. One counted wait vmcnt(10) per iter (never 0 until tail).
__global__ __launch_bounds__(512) void bmm_prelu_kernel(
    const float* __restrict__ adj, const ushort* __restrict__ hT,
    const float* __restrict__ alphaP, float* __restrict__ out) {
  __shared__ __align__(16) ushort lA[2][64 * 64];   // 16 KB
  __shared__ __align__(16) ushort lB[4][256 * 64];  // 128 KB

  const int tid = threadIdx.x;
  const int lane = tid & 63;
  const int wid = tid >> 6;
  const int wm = wid >> 2, wn = wid & 3;

  // XCD-contiguous remap (bijective: 256 = 8 * 32).
  const int bid = blockIdx.x;
  const int sbid = (bid & 7) * 32 + (bid >> 3);
  const int batch = sbid >> 6;
  const int m0 = (sbid & 63) * 64;

  const float* adjB = adj + (size_t)batch * NSEQ * NSEQ + (size_t)m0 * NSEQ;
  const ushort* hTB = hT + (size_t)batch * FT * NSEQ;

  const int ar = tid >> 4, ac = tid & 15;      // adj staging geometry
  const int brow = wid * 8 + (lane >> 3);      // hT row (+ p*64)
  const int bg = (lane & 7) ^ (lane >> 3);     // pre-swizzled source granule

  f32x4 rA0[2], rA1[2];

  f32x4 acc[2][4];
  const f32x4 zero = {0.f, 0.f, 0.f, 0.f};
#pragma unroll
  for (int mi = 0; mi < 2; ++mi)
#pragma unroll
    for (int ni = 0; ni < 4; ++ni) acc[mi][ni] = zero;

  auto issueA = [&](int t, f32x4* r) {
    const int k0 = t * BK;
#pragma unroll
    for (int p = 0; p < 2; ++p)
      r[p] = __builtin_nontemporal_load(reinterpret_cast<const f32x4*>(
          adjB + (size_t)(ar + p * 32) * NSEQ + k0 + ac * 4));
  };
  auto issueB = [&](int t, int ib) {
    const int k0 = t * BK;
#pragma unroll
    for (int p = 0; p < 4; ++p) {
      const ushort* gp = hTB + (size_t)(p * 64 + brow) * NSEQ + k0 + bg * 8;
      ushort* lp = &lB[ib][p * 4096 + wid * 512];
      __builtin_amdgcn_global_load_lds(
          (const __attribute__((address_space(1))) void*)gp,
          (__attribute__((address_space(3))) void*)lp, 16, 0, 0);
    }
  };
  auto writeA = [&](const f32x4* r, int ia) {
    char* lAp = (char*)lA[ia];
#pragma unroll
    for (int p = 0; p < 2; ++p) {
      ushort4 u = make_ushort4(f2bf(r[p][0]), f2bf(r[p][1]), f2bf(r[p][2]), f2bf(r[p][3]));
      *reinterpret_cast<ushort4*>(lAp + swz(ar + p * 32, ac * 8)) = u;
    }
  };

  // Prologue. Queue (oldest->newest): A0(2) B0(4) B1(4) A1(2) B2(4) = 16.
  issueA(0, rA0);
  issueB(0, 0);
  issueB(1, 1);
  issueA(1, rA1);
  issueB(2, 2);
  asm volatile("s_waitcnt vmcnt(14)" ::: "memory");  // A0 regs ready
  writeA(rA0, 0);
  asm volatile("s_waitcnt vmcnt(10) lgkmcnt(0)" ::: "memory");  // B0 in LDS
  __builtin_amdgcn_s_barrier();
  __builtin_amdgcn_sched_barrier(0);

  // body(t): issue A(t+2)->rA[t&1], B(t+3)->lB[(t+3)%4];
  //          mma on lA[t&1], lB[t%4];
  //          vmcnt(10) drains exactly B(t+1)+A(t+1);
  //          writeA rA[(t+1)&1] -> lA[(t+1)&1]; lgkm0; barrier.
  auto body = [&](int t, f32x4* rIssue, f32x4* rWrite,
                  int ibIssue, int ibRead, int iaRead, int iaWrite) {
    issueA(t + 2, rIssue);
    issueB(t + 3, ibIssue);
    mma_step((const char*)lA[iaRead], (const char*)lB[ibRead], lane, wm, wn, acc);
    asm volatile("s_waitcnt vmcnt(10)" ::: "memory");
    writeA(rWrite, iaWrite);
    asm volatile("s_waitcnt lgkmcnt(0)" ::: "memory");
    __builtin_amdgcn_s_barrier();
    __builtin_amdgcn_sched_barrier(0);
  };

  // t = 0..59 in groups of 4 (all indices compile-time static).
  for (int j = 0; j < 15; ++j) {
    body(j * 4 + 0, rA0, rA1, 3, 0, 0, 1);
    body(j * 4 + 1, rA1, rA0, 0, 1, 1, 0);
    body(j * 4 + 2, rA0, rA1, 1, 2, 0, 1);
    body(j * 4 + 3, rA1, rA0, 2, 3, 1, 0);
  }
  // t = 60 (last full body)
  body(60, rA0, rA1, 3, 0, 0, 1);
  {  // t = 61: issue A(63) only. Queue: B62(4) A62(2) B63(4) A63(2) = 12.
    issueA(63, rA1);
    mma_step((const char*)lA[1], (const char*)lB[1], lane, wm, wn, acc);
    asm volatile("s_waitcnt vmcnt(6)" ::: "memory");  // B62 + A62 done
    writeA(rA0, 0);
    asm volatile("s_waitcnt lgkmcnt(0)" ::: "memory");
    __builtin_amdgcn_s_barrier();
    __builtin_amdgcn_sched_barrier(0);
  }
  {  // t = 62
    mma_step((const char*)lA[0], (const char*)lB[2], lane, wm, wn, acc);
    asm volatile("s_waitcnt vmcnt(0)" ::: "memory");  // B63 + A63 done
    writeA(rA1, 1);
    asm volatile("s_waitcnt lgkmcnt(0)" ::: "memory");
    __builtin_amdgcn_s_barrier();
    __builtin_amdgcn_sched_barrier(0);
  }
  // t = 63
  mma_step((const char*)lA[1], (const char*)lB[3], lane, wm, wn, acc);

  // Epilogue: PReLU -> LDS (overlay on lB, padded pitch) -> coalesced rows.
  const float alpha = *alphaP;
  __syncthreads();
  float* lo = (float*)&lB[0][0];  // 64 x 264 f32 = 66 KB (fits in 128 KB lB)
  const int PITCH = 264;
#pragma unroll
  for (int mi = 0; mi < 2; ++mi) {
    const int rbase = wm * 32 + mi * 16 + ((lane >> 4) << 2);
#pragma unroll
    for (int ni = 0; ni < 4; ++ni) {
      const int o = wn * 64 + ni * 16 + (lane & 15);
#pragma unroll
      for (int j = 0; j < 4; ++j) {
        float v = acc[mi][ni][j];
        v = v > 0.f ? v : alpha * v;
        lo[(rbase + j) * PITCH + o] = v;
      }
    }
  }
  __syncthreads();
  float* outB = out + ((size_t)batch * NSEQ + m0) * FT;
  const int r = tid >> 3, c8 = tid & 7;
#pragma unroll
  for (int k = 0; k < 8; ++k) {
    const int g = c8 + k * 8;
    f32x4 v = *reinterpret_cast<const f32x4*>(lo + r * PITCH + g * 4);
    __builtin_nontemporal_store(v, reinterpret_cast<f32x4*>(outB + (size_t)r * FT + g * 4));
  }
}

extern "C" void kernel_launch(void* const* d_in, const int* in_sizes, int n_in,
                              void* d_out, int out_size, void* d_ws, size_t ws_size,
                              hipStream_t stream) {
  const float* seq = (const float*)d_in[0];
  const float* adj = (const float*)d_in[1];
  const float* W = (const float*)d_in[2];
  const float* bias = (const float*)d_in[3];
  const float* alpha = (const float*)d_in[4];
  float* out = (float*)d_out;
  ushort* hT = (ushort*)d_ws;  // [4][256][4096] bf16 = 8 MB

  linear_kernel<<<256, 512, 0, stream>>>(seq, W, bias, hT);
  bmm_prelu_kernel<<<256, 512, 0, stream>>>(adj, hT, alpha, out);
}